// Round 8
// baseline (496.129 us; speedup 1.0000x reference)
//
#include <hip/hip_runtime.h>
#include <hip/hip_bf16.h>
#include <stdint.h>

// ---------- types / helpers ----------
typedef __bf16 bf16x8_t __attribute__((ext_vector_type(8)));
typedef float f32x4_t __attribute__((ext_vector_type(4)));
typedef unsigned short ushort8_t __attribute__((ext_vector_type(8)));  // 16B aligned

__device__ __forceinline__ unsigned short f2bf(float f) {
    union { float f; uint32_t i; } v; v.f = f;
    uint32_t i = v.i + (((v.i >> 16) & 1u) + 0x7FFFu);   // RNE
    return (unsigned short)(i >> 16);
}

// ---------- problem constants ----------
#define BB   256
#define CC   3
#define HH   128
#define WW   128
#define PP   768        // C*K*K
#define HID  2048
#define LL   256
#define MM   16384      // B*GH*GW
#define MC   8192       // chunk rows (2 chunks, processed in REVERSE order)

// ---------- patchify: x f32 (B,C,H,W) -> patches bf16 (M,768), u16-view of out0 ----------
__global__ void patchify(const float* __restrict__ x,
                         unsigned short* __restrict__ patches) {
    int t = blockIdx.x * 256 + threadIdx.x;        // 1,572,864 threads, 8 elems each
    int e = t * 8;                                  // linear index into x
    int col = e & 127;                              // w (multiple of 8)
    int row = (e >> 7) & 127;                       // h
    int c   = (e >> 14) % 3;
    int b   = e / (128 * 128 * 3);
    int gh = row >> 4, kh = row & 15, gw = col >> 4, kw = col & 15;
    long po = (long)(b * 64 + gh * 8 + gw) * PP + c * 256 + kh * 16 + kw;
    float4 v0 = *(const float4*)(x + e);
    float4 v1 = *(const float4*)(x + e + 4);
    ushort8_t o;
    o[0] = f2bf(v0.x); o[1] = f2bf(v0.y); o[2] = f2bf(v0.z); o[3] = f2bf(v0.w);
    o[4] = f2bf(v1.x); o[5] = f2bf(v1.y); o[6] = f2bf(v1.z); o[7] = f2bf(v1.w);
    *(ushort8_t*)(patches + po) = o;
}

// ---------- 32x32-tiled transpose + cast: out bf16[c*R+r] = in f32[r*C+c] ----------
__global__ void transpose_k(const float* __restrict__ in,
                            unsigned short* __restrict__ out, int R, int C) {
    __shared__ unsigned short tile[32][34];
    int nbc = C >> 5;
    int tc = blockIdx.x % nbc, tr = blockIdx.x / nbc;
    int tx = threadIdx.x & 31, ty0 = threadIdx.x >> 5;   // 8 rows/pass
    int r0 = tr << 5, c0 = tc << 5;
    #pragma unroll
    for (int i = 0; i < 4; ++i) {
        int ty = ty0 + i * 8;
        tile[ty][tx] = f2bf(in[(long)(r0 + ty) * C + c0 + tx]);
    }
    __syncthreads();
    #pragma unroll
    for (int i = 0; i < 4; ++i) {
        int ty = ty0 + i * 8;
        out[(long)(c0 + ty) * R + r0 + tx] = tile[tx][ty];
    }
}

// ---------- GEMM: C(rows x N) = act(A(rows x K) @ Bt(N x K)^T + bias f32) ----------
// A,Bt bf16; fp32 accumulate. 128x128 tile, BK=32, 4 waves (2x2), wave 4x4 MFMA
// 16x16x32. ACT: 0=none 1=relu 2=sigmoid.
// WMODE 0: bf16 C0u[m*ldc+n]                              (he / hd scratch)
// WMODE 1: f32 C1f[((gm>>6)*512+n)*64+(gm&63)] (gm=m0+m)  (mu_logvar_2d out1)
//          + bf16 C0u[m*256+n] for n<256                  (compact mu scratch)
// WMODE 2: f32 unpatchify scatter into C0f = (B,C,H,W), rows gm=m0+m
template <int ACT, int WMODE>
__global__ void __launch_bounds__(256)
gemm_bt(const unsigned short* __restrict__ A, int lda,
        const unsigned short* __restrict__ Bt,
        const float* __restrict__ bias,
        unsigned short* __restrict__ C0u,
        float* __restrict__ C0f,
        float* __restrict__ C1f,
        int ldc, int Kd, int nbn, int m0) {
    __shared__ __align__(16) unsigned short As[128 * 32];
    __shared__ __align__(16) unsigned short Bs[128 * 32];
    const int bn = blockIdx.x % nbn;
    const int bm = blockIdx.x / nbn;
    const int tid = threadIdx.x;
    const int wave = tid >> 6;
    const int lane = tid & 63;
    const int wm = (wave >> 1) << 6;     // wave row offset
    const int wn = (wave & 1) << 6;      // wave col offset
    const int sr = tid >> 2;             // staging row 0..63
    const int sc = (tid & 3) << 3;       // staging col {0,8,16,24}
    const unsigned short* Ab = A + (long)(bm * 128) * lda;
    const unsigned short* Bb = Bt + (long)(bn * 128) * Kd;

    f32x4_t acc[4][4];
    #pragma unroll
    for (int i = 0; i < 4; ++i)
        #pragma unroll
        for (int j = 0; j < 4; ++j)
            acc[i][j] = (f32x4_t){0.f, 0.f, 0.f, 0.f};

    const int fr = lane & 15;            // fragment row (m for A, n for B)
    const int kg = (lane >> 4) << 3;     // fragment k-offset: quad*8

    for (int k0 = 0; k0 < Kd; k0 += 32) {
        uint4 a0 = *(const uint4*)(Ab + (long)sr * lda + k0 + sc);
        uint4 a1 = *(const uint4*)(Ab + (long)(sr + 64) * lda + k0 + sc);
        uint4 b0 = *(const uint4*)(Bb + (long)sr * Kd + k0 + sc);
        uint4 b1 = *(const uint4*)(Bb + (long)(sr + 64) * Kd + k0 + sc);
        __syncthreads();   // previous iteration's fragment reads complete
        *(uint4*)&As[(sr << 5) + sc] = a0;
        *(uint4*)&As[((sr + 64) << 5) + sc] = a1;
        *(uint4*)&Bs[(sr << 5) + sc] = b0;
        *(uint4*)&Bs[((sr + 64) << 5) + sc] = b1;
        __syncthreads();   // staging visible to all waves
        bf16x8_t af[4], bfr[4];
        #pragma unroll
        for (int i = 0; i < 4; ++i)
            af[i] = *(const bf16x8_t*)&As[((wm + (i << 4) + fr) << 5) + kg];
        #pragma unroll
        for (int j = 0; j < 4; ++j)
            bfr[j] = *(const bf16x8_t*)&Bs[((wn + (j << 4) + fr) << 5) + kg];
        #pragma unroll
        for (int i = 0; i < 4; ++i)
            #pragma unroll
            for (int j = 0; j < 4; ++j)
                acc[i][j] = __builtin_amdgcn_mfma_f32_16x16x32_bf16(
                    af[i], bfr[j], acc[i][j], 0, 0, 0);
    }

    // epilogue — C/D layout: col = lane&15, row = (lane>>4)*4 + reg
    const int gcol0 = bn * 128 + wn;
    const int grow0 = bm * 128 + wm;
    #pragma unroll
    for (int j = 0; j < 4; ++j) {
        const int n = gcol0 + (j << 4) + (lane & 15);
        const float bv = bias[n];
        #pragma unroll
        for (int i = 0; i < 4; ++i) {
            #pragma unroll
            for (int r = 0; r < 4; ++r) {
                const int m = grow0 + (i << 4) + ((lane >> 4) << 2) + r;
                float v = acc[i][j][r] + bv;
                if (ACT == 1) v = fmaxf(v, 0.f);
                if (ACT == 2) v = 1.f / (1.f + __expf(-v));
                if (WMODE == 0) {
                    C0u[(long)m * ldc + n] = f2bf(v);
                } else if (WMODE == 1) {
                    const int gm = m0 + m;
                    C1f[((long)(gm >> 6) * 512 + n) * 64 + (gm & 63)] = v;
                    if (n < 256) C0u[(long)m * 256 + n] = f2bf(v);
                } else {
                    const int gm = m0 + m;
                    const int b = gm >> 6, g6 = gm & 63;
                    const int gh = g6 >> 3, gw = g6 & 7;
                    const int c = n >> 8, kh = (n >> 4) & 15, kw = n & 15;
                    const long o = (long)(b * 3 + c) * 16384
                                 + ((gh << 4) + kh) * 128 + (gw << 4) + kw;
                    C0f[o] = v;
                }
            }
        }
    }
}

// ---------- launch ----------
extern "C" void kernel_launch(void* const* d_in, const int* in_sizes, int n_in,
                              void* d_out, int out_size, void* d_ws, size_t ws_size,
                              hipStream_t stream) {
    // inputs f32 (per reference); output f32 (per round-2 value-bound proof)
    const float* x      = (const float*)d_in[0];
    const float* w_enc1 = (const float*)d_in[1];
    const float* b_enc1 = (const float*)d_in[2];
    const float* w_enc2 = (const float*)d_in[3];
    const float* b_enc2 = (const float*)d_in[4];
    const float* w_dec1 = (const float*)d_in[5];
    const float* b_dec1 = (const float*)d_in[6];
    const float* w_dec2 = (const float*)d_in[7];
    const float* b_dec2 = (const float*)d_in[8];
    float* outf = (float*)d_out;                      // f32 output
    (void)d_ws; (void)ws_size;                        // d_ws never touched

    // out0 (f32 [0,12.58M)) doubles as patches scratch via its u16 view:
    // patches bf16 occupy u16 slots [0,12.58M) = f32 slots [0,6.29M).
    // Chunks run in REVERSE order so GEMM4's f32 writes (f32 slots
    // [m0/64*49152 ...)) never land on patches a later chunk still needs.
    unsigned short* patches = (unsigned short*)d_out;
    float* out_ml = outf + (long)MM * PP;             // f32 [12.58M, 20.97M)

    // x's buffer (12.58M f32 = 25.17M u16) is dead after patchify -> scratch.
    // u16 layout: wT1 1.57M | wT2 1.05M | wT3 0.52M | wT4 1.57M |
    //             mu MC*256=2.10M | he/hd MC*2048=16.78M -> 23.59M <= 25.17M
    unsigned short* xb  = (unsigned short*)d_in[0];
    unsigned short* wT1 = xb;                         // 2048*768
    unsigned short* wT2 = wT1 + 2048 * 768;           // 512*2048
    unsigned short* wT3 = wT2 + 512 * 2048;           // 2048*256
    unsigned short* wT4 = wT3 + 2048 * 256;           // 768*2048
    unsigned short* mu  = wT4 + 768 * 2048;           // MC*256
    unsigned short* he  = mu + (long)MC * LL;         // MC*2048 (hd aliases he)

    // 1) consume x into out0's u16 view
    patchify<<<6144, 256, 0, stream>>>(x, patches);

    // 2) weight transposes + cast (K x N -> N x K) into x's buffer (now dead)
    transpose_k<<<(768 / 32) * (2048 / 32), 256, 0, stream>>>(w_enc1, wT1, 768, 2048);
    transpose_k<<<(2048 / 32) * (512 / 32), 256, 0, stream>>>(w_enc2, wT2, 2048, 512);
    transpose_k<<<(256 / 32) * (2048 / 32), 256, 0, stream>>>(w_dec1, wT3, 256, 2048);
    transpose_k<<<(2048 / 32) * (768 / 32), 256, 0, stream>>>(w_dec2, wT4, 2048, 768);

    // 3) chunks over M in REVERSE order (m0 = 8192, then 0)
    const int nbm = MC / 128;   // 64
    for (long m0 = MM - MC; m0 >= 0; m0 -= MC) {
        // he = relu(patches[m0:] @ w_enc1 + b_enc1)      MC x 2048, K=768
        gemm_bt<1, 0><<<nbm * (HID / 128), 256, 0, stream>>>(
            patches + m0 * PP, PP, wT1, b_enc1,
            he, nullptr, nullptr, HID, PP, HID / 128, 0);
        // ml = he @ w_enc2 + b_enc2 -> out1 f32 (transposed) + compact bf16 mu
        gemm_bt<0, 1><<<nbm * (512 / 128), 256, 0, stream>>>(
            he, HID, wT2, b_enc2,
            mu, nullptr, out_ml, 0, HID, 512 / 128, (int)m0);
        // hd = relu(mu @ w_dec1 + b_dec1)                MC x 2048, K=256
        gemm_bt<1, 0><<<nbm * (HID / 128), 256, 0, stream>>>(
            mu, LL, wT3, b_dec1,
            he, nullptr, nullptr, HID, LL, HID / 128, 0);
        // recon rows m0.. = sigmoid(hd @ w_dec2 + b_dec2) -> f32 scatter out0
        gemm_bt<2, 2><<<nbm * (PP / 128), 256, 0, stream>>>(
            he, HID, wT4, b_dec2,
            nullptr, outf, nullptr, 0, HID, PP / 128, (int)m0);
    }
}

// Round 9
// 486.028 us; speedup vs baseline: 1.0208x; 1.0208x over previous
//
#include <hip/hip_runtime.h>
#include <hip/hip_bf16.h>
#include <stdint.h>

// ---------- types / helpers ----------
typedef __bf16 bf16x8_t __attribute__((ext_vector_type(8)));
typedef float f32x4_t __attribute__((ext_vector_type(4)));
typedef unsigned short ushort8_t __attribute__((ext_vector_type(8)));  // 16B aligned

__device__ __forceinline__ unsigned short f2bf(float f) {
    union { float f; uint32_t i; } v; v.f = f;
    uint32_t i = v.i + (((v.i >> 16) & 1u) + 0x7FFFu);   // RNE
    return (unsigned short)(i >> 16);
}

typedef const __attribute__((address_space(1))) void* gas_t;
typedef __attribute__((address_space(3))) void* las_t;
__device__ __forceinline__ void load_lds16(const unsigned short* g, unsigned short* l) {
    // async global->LDS DMA; LDS dest = wave-uniform base + lane*16B
    __builtin_amdgcn_global_load_lds((gas_t)g, (las_t)l, 16, 0, 0);
}

// ---------- problem constants ----------
#define BB   256
#define CC   3
#define HH   128
#define WW   128
#define PP   768        // C*K*K
#define HID  2048
#define LL   256
#define MM   16384      // B*GH*GW
#define MC   8192       // chunk rows (2 chunks, processed in REVERSE order)

// ---------- patchify: x f32 (B,C,H,W) -> patches bf16 (M,768), u16-view of out0 ----------
__global__ void patchify(const float* __restrict__ x,
                         unsigned short* __restrict__ patches) {
    int t = blockIdx.x * 256 + threadIdx.x;        // 1,572,864 threads, 8 elems each
    int e = t * 8;                                  // linear index into x
    int col = e & 127;                              // w (multiple of 8)
    int row = (e >> 7) & 127;                       // h
    int c   = (e >> 14) % 3;
    int b   = e / (128 * 128 * 3);
    int gh = row >> 4, kh = row & 15, gw = col >> 4, kw = col & 15;
    long po = (long)(b * 64 + gh * 8 + gw) * PP + c * 256 + kh * 16 + kw;
    float4 v0 = *(const float4*)(x + e);
    float4 v1 = *(const float4*)(x + e + 4);
    ushort8_t o;
    o[0] = f2bf(v0.x); o[1] = f2bf(v0.y); o[2] = f2bf(v0.z); o[3] = f2bf(v0.w);
    o[4] = f2bf(v1.x); o[5] = f2bf(v1.y); o[6] = f2bf(v1.z); o[7] = f2bf(v1.w);
    *(ushort8_t*)(patches + po) = o;
}

// ---------- 32x32-tiled transpose + cast: out bf16[c*R+r] = in f32[r*C+c] ----------
__global__ void transpose_k(const float* __restrict__ in,
                            unsigned short* __restrict__ out, int R, int C) {
    __shared__ unsigned short tile[32][34];
    int nbc = C >> 5;
    int tc = blockIdx.x % nbc, tr = blockIdx.x / nbc;
    int tx = threadIdx.x & 31, ty0 = threadIdx.x >> 5;   // 8 rows/pass
    int r0 = tr << 5, c0 = tc << 5;
    #pragma unroll
    for (int i = 0; i < 4; ++i) {
        int ty = ty0 + i * 8;
        tile[ty][tx] = f2bf(in[(long)(r0 + ty) * C + c0 + tx]);
    }
    __syncthreads();
    #pragma unroll
    for (int i = 0; i < 4; ++i) {
        int ty = ty0 + i * 8;
        out[(long)(c0 + ty) * R + r0 + tx] = tile[tx][ty];
    }
}

// ---------- GEMM: C(rows x N) = act(A(rows x K) @ Bt(N x K)^T + bias f32) ----------
// A,Bt bf16; fp32 accumulate. 128x128 tile, BK=32, 4 waves (2x2), wave 4x4 MFMA
// 16x16x32. global_load_lds width-16 staging. XCD-swizzled block mapping:
// each XCD owns a contiguous bm-stripe (nbm/8 rows) x all bn -> A fetched once
// chip-wide, B once per XCD.  ACT: 0=none 1=relu 2=sigmoid.
// WMODE 0: bf16 C0u[m*ldc+n]                              (he / hd scratch)
// WMODE 1: f32 C1f[((gm>>6)*512+n)*64+(gm&63)] (gm=m0+m)  (mu_logvar_2d out1)
//          + bf16 C0u[m*256+n] for n<256                  (compact mu scratch)
// WMODE 2: f32 unpatchify scatter into C0f = (B,C,H,W), rows gm=m0+m
template <int ACT, int WMODE>
__global__ void __launch_bounds__(256)
gemm_bt(const unsigned short* __restrict__ A, int lda,
        const unsigned short* __restrict__ Bt,
        const float* __restrict__ bias,
        unsigned short* __restrict__ C0u,
        float* __restrict__ C0f,
        float* __restrict__ C1f,
        int ldc, int Kd, int nbn, int m0) {
    __shared__ __align__(16) unsigned short As[128 * 32];
    __shared__ __align__(16) unsigned short Bs[128 * 32];
    // XCD-aware swizzle (bid&7 ~ XCD round-robin heuristic; perf-only)
    const int nbm = gridDim.x / nbn;
    const int stripe = nbm >> 3;                 // bm rows per XCD
    const int xcd = blockIdx.x & 7;
    const int loc = blockIdx.x >> 3;
    const int bm = xcd * stripe + (loc % stripe);
    const int bn = loc / stripe;
    const int tid = threadIdx.x;
    const int wave = tid >> 6;
    const int lane = tid & 63;
    const int wm = (wave >> 1) << 6;             // wave row offset
    const int wn = (wave & 1) << 6;              // wave col offset
    // async-staging addressing: wave w stages rows [w*16, w*16+16) + the +64 half
    const int r0 = (wave << 4) + (lane >> 2);    // row 0..63
    const int cc = (lane & 3) << 3;              // col {0,8,16,24}
    unsigned short* ldsA0 = As + (wave << 9);            // wave*512 halfwords
    unsigned short* ldsA1 = As + (wave << 9) + 2048;     // +64 rows
    unsigned short* ldsB0 = Bs + (wave << 9);
    unsigned short* ldsB1 = Bs + (wave << 9) + 2048;
    const unsigned short* Ab = A + (long)(bm * 128) * lda;
    const unsigned short* Bb = Bt + (long)(bn * 128) * Kd;

    f32x4_t acc[4][4];
    #pragma unroll
    for (int i = 0; i < 4; ++i)
        #pragma unroll
        for (int j = 0; j < 4; ++j)
            acc[i][j] = (f32x4_t){0.f, 0.f, 0.f, 0.f};

    const int fr = lane & 15;            // fragment row (m for A, n for B)
    const int kg = (lane >> 4) << 3;     // fragment k-offset: quad*8

    for (int k0 = 0; k0 < Kd; k0 += 32) {
        load_lds16(Ab + (long)r0 * lda + k0 + cc, ldsA0);
        load_lds16(Ab + (long)(r0 + 64) * lda + k0 + cc, ldsA1);
        load_lds16(Bb + (long)r0 * Kd + k0 + cc, ldsB0);
        load_lds16(Bb + (long)(r0 + 64) * Kd + k0 + cc, ldsB1);
        __syncthreads();   // drains vmcnt before barrier -> staging complete
        bf16x8_t af[4], bfr[4];
        #pragma unroll
        for (int i = 0; i < 4; ++i)
            af[i] = *(const bf16x8_t*)&As[((wm + (i << 4) + fr) << 5) + kg];
        #pragma unroll
        for (int j = 0; j < 4; ++j)
            bfr[j] = *(const bf16x8_t*)&Bs[((wn + (j << 4) + fr) << 5) + kg];
        #pragma unroll
        for (int i = 0; i < 4; ++i)
            #pragma unroll
            for (int j = 0; j < 4; ++j)
                acc[i][j] = __builtin_amdgcn_mfma_f32_16x16x32_bf16(
                    af[i], bfr[j], acc[i][j], 0, 0, 0);
        __syncthreads();   // all waves done reading before next staging
    }

    // epilogue — C/D layout: col = lane&15, row = (lane>>4)*4 + reg
    const int gcol0 = bn * 128 + wn;
    const int grow0 = bm * 128 + wm;
    #pragma unroll
    for (int j = 0; j < 4; ++j) {
        const int n = gcol0 + (j << 4) + (lane & 15);
        const float bv = bias[n];
        #pragma unroll
        for (int i = 0; i < 4; ++i) {
            #pragma unroll
            for (int r = 0; r < 4; ++r) {
                const int m = grow0 + (i << 4) + ((lane >> 4) << 2) + r;
                float v = acc[i][j][r] + bv;
                if (ACT == 1) v = fmaxf(v, 0.f);
                if (ACT == 2) v = 1.f / (1.f + __expf(-v));
                if (WMODE == 0) {
                    C0u[(long)m * ldc + n] = f2bf(v);
                } else if (WMODE == 1) {
                    const int gm = m0 + m;
                    C1f[((long)(gm >> 6) * 512 + n) * 64 + (gm & 63)] = v;
                    if (n < 256) C0u[(long)m * 256 + n] = f2bf(v);
                } else {
                    const int gm = m0 + m;
                    const int b = gm >> 6, g6 = gm & 63;
                    const int gh = g6 >> 3, gw = g6 & 7;
                    const int c = n >> 8, kh = (n >> 4) & 15, kw = n & 15;
                    const long o = (long)(b * 3 + c) * 16384
                                 + ((gh << 4) + kh) * 128 + (gw << 4) + kw;
                    C0f[o] = v;
                }
            }
        }
    }
}

// ---------- launch ----------
extern "C" void kernel_launch(void* const* d_in, const int* in_sizes, int n_in,
                              void* d_out, int out_size, void* d_ws, size_t ws_size,
                              hipStream_t stream) {
    const float* x      = (const float*)d_in[0];
    const float* w_enc1 = (const float*)d_in[1];
    const float* b_enc1 = (const float*)d_in[2];
    const float* w_enc2 = (const float*)d_in[3];
    const float* b_enc2 = (const float*)d_in[4];
    const float* w_dec1 = (const float*)d_in[5];
    const float* b_dec1 = (const float*)d_in[6];
    const float* w_dec2 = (const float*)d_in[7];
    const float* b_dec2 = (const float*)d_in[8];
    float* outf = (float*)d_out;                      // f32 output
    (void)d_ws; (void)ws_size;                        // d_ws never touched

    // out0 (f32 [0,12.58M)) doubles as patches scratch via its u16 view.
    // Chunks run in REVERSE order so GEMM4's f32 writes never land on
    // patches a later chunk still needs.
    unsigned short* patches = (unsigned short*)d_out;
    float* out_ml = outf + (long)MM * PP;             // f32 [12.58M, 20.97M)

    // x's buffer (25.17M u16) is dead after patchify -> scratch.
    unsigned short* xb  = (unsigned short*)d_in[0];
    unsigned short* wT1 = xb;                         // 2048*768
    unsigned short* wT2 = wT1 + 2048 * 768;           // 512*2048
    unsigned short* wT3 = wT2 + 512 * 2048;           // 2048*256
    unsigned short* wT4 = wT3 + 2048 * 256;           // 768*2048
    unsigned short* mu  = wT4 + 768 * 2048;           // MC*256
    unsigned short* he  = mu + (long)MC * LL;         // MC*2048 (hd aliases he)

    patchify<<<6144, 256, 0, stream>>>(x, patches);

    transpose_k<<<(768 / 32) * (2048 / 32), 256, 0, stream>>>(w_enc1, wT1, 768, 2048);
    transpose_k<<<(2048 / 32) * (512 / 32), 256, 0, stream>>>(w_enc2, wT2, 2048, 512);
    transpose_k<<<(256 / 32) * (2048 / 32), 256, 0, stream>>>(w_dec1, wT3, 256, 2048);
    transpose_k<<<(2048 / 32) * (768 / 32), 256, 0, stream>>>(w_dec2, wT4, 2048, 768);

    const int nbm = MC / 128;   // 64
    for (long m0 = MM - MC; m0 >= 0; m0 -= MC) {
        // he = relu(patches[m0:] @ w_enc1 + b_enc1)      MC x 2048, K=768
        gemm_bt<1, 0><<<nbm * (HID / 128), 256, 0, stream>>>(
            patches + m0 * PP, PP, wT1, b_enc1,
            he, nullptr, nullptr, HID, PP, HID / 128, 0);
        // ml = he @ w_enc2 + b_enc2 -> out1 f32 (transposed) + compact bf16 mu
        gemm_bt<0, 1><<<nbm * (512 / 128), 256, 0, stream>>>(
            he, HID, wT2, b_enc2,
            mu, nullptr, out_ml, 0, HID, 512 / 128, (int)m0);
        // hd = relu(mu @ w_dec1 + b_dec1)                MC x 2048, K=256
        gemm_bt<1, 0><<<nbm * (HID / 128), 256, 0, stream>>>(
            mu, LL, wT3, b_dec1,
            he, nullptr, nullptr, HID, LL, HID / 128, 0);
        // recon rows m0.. = sigmoid(hd @ w_dec2 + b_dec2) -> f32 scatter out0
        gemm_bt<2, 2><<<nbm * (PP / 128), 256, 0, stream>>>(
            he, HID, wT4, b_dec2,
            nullptr, outf, nullptr, 0, HID, PP / 128, (int)m0);
    }
}

// Round 10
// 383.490 us; speedup vs baseline: 1.2937x; 1.2674x over previous
//
#include <hip/hip_runtime.h>
#include <hip/hip_bf16.h>
#include <stdint.h>

// ---------- types / helpers ----------
typedef __bf16 bf16x8_t __attribute__((ext_vector_type(8)));
typedef float f32x4_t __attribute__((ext_vector_type(4)));
typedef unsigned short ushort8_t __attribute__((ext_vector_type(8)));  // 16B aligned

__device__ __forceinline__ unsigned short f2bf(float f) {
    union { float f; uint32_t i; } v; v.f = f;
    uint32_t i = v.i + (((v.i >> 16) & 1u) + 0x7FFFu);   // RNE
    return (unsigned short)(i >> 16);
}

typedef const __attribute__((address_space(1))) void* gas_t;
typedef __attribute__((address_space(3))) void* las_t;
__device__ __forceinline__ void load_lds16(const unsigned short* g, unsigned short* l) {
    // async global->LDS DMA; LDS dest = wave-uniform base + lane*16B
    __builtin_amdgcn_global_load_lds((gas_t)g, (las_t)l, 16, 0, 0);
}

// ---------- problem constants ----------
#define BB   256
#define CC   3
#define HH   128
#define WW   128
#define PP   768        // C*K*K
#define HID  2048
#define LL   256
#define MM   16384      // B*GH*GW

// ---------- patchify: x f32 (B,C,H,W) -> patches bf16 (M,768), u16-view of out0 ----------
__global__ void patchify(const float* __restrict__ x,
                         unsigned short* __restrict__ patches) {
    int t = blockIdx.x * 256 + threadIdx.x;        // 1,572,864 threads, 8 elems each
    int e = t * 8;                                  // linear index into x
    int col = e & 127;                              // w (multiple of 8)
    int row = (e >> 7) & 127;                       // h
    int c   = (e >> 14) % 3;
    int b   = e / (128 * 128 * 3);
    int gh = row >> 4, kh = row & 15, gw = col >> 4, kw = col & 15;
    long po = (long)(b * 64 + gh * 8 + gw) * PP + c * 256 + kh * 16 + kw;
    float4 v0 = *(const float4*)(x + e);
    float4 v1 = *(const float4*)(x + e + 4);
    ushort8_t o;
    o[0] = f2bf(v0.x); o[1] = f2bf(v0.y); o[2] = f2bf(v0.z); o[3] = f2bf(v0.w);
    o[4] = f2bf(v1.x); o[5] = f2bf(v1.y); o[6] = f2bf(v1.z); o[7] = f2bf(v1.w);
    *(ushort8_t*)(patches + po) = o;
}

// ---------- 32x32-tiled transpose + cast: out bf16[c*R+r] = in f32[r*C+c] ----------
__global__ void transpose_k(const float* __restrict__ in,
                            unsigned short* __restrict__ out, int R, int C) {
    __shared__ unsigned short tile[32][34];
    int nbc = C >> 5;
    int tc = blockIdx.x % nbc, tr = blockIdx.x / nbc;
    int tx = threadIdx.x & 31, ty0 = threadIdx.x >> 5;   // 8 rows/pass
    int r0 = tr << 5, c0 = tc << 5;
    #pragma unroll
    for (int i = 0; i < 4; ++i) {
        int ty = ty0 + i * 8;
        tile[ty][tx] = f2bf(in[(long)(r0 + ty) * C + c0 + tx]);
    }
    __syncthreads();
    #pragma unroll
    for (int i = 0; i < 4; ++i) {
        int ty = ty0 + i * 8;
        out[(long)(c0 + ty) * R + r0 + tx] = tile[tx][ty];
    }
}

// ---------- GEMM: C(rows x N) = act(A(rows x K) @ Bt(N x K)^T + bias f32) ----------
// A,Bt bf16; fp32 accumulate. 128x128 tile, BK=64, 4 waves (2x2), wave 4x4 MFMA
// 16x16x32 (x2 k-halves per barrier). global_load_lds width-16 staging into an
// XOR-swizzled LDS layout: logical col-group g of row r stored at phys group
// g^(r&7) -> fragment ds_read_b128 is 2-way bank-aliased (free). XCD-swizzled
// block mapping (bid&7 round-robin): each XCD owns a contiguous bm-stripe.
// ACT: 0=none 1=relu 2=sigmoid.
// WMODE 0: bf16 C0u[m*ldc+n]                              (he / hd scratch)
// WMODE 1: f32 C1f[((gm>>6)*512+n)*64+(gm&63)] (gm=m0+m)  (mu_logvar_2d out1)
//          + bf16 C0u[m*256+n] for n<256                  (compact mu scratch)
// WMODE 2: f32 unpatchify scatter into C0f = (B,C,H,W), rows gm=m0+m
template <int ACT, int WMODE>
__global__ void __launch_bounds__(256)
gemm_bt(const unsigned short* __restrict__ A, int lda,
        const unsigned short* __restrict__ Bt,
        const float* __restrict__ bias,
        unsigned short* __restrict__ C0u,
        float* __restrict__ C0f,
        float* __restrict__ C1f,
        int ldc, int Kd, int nbn, int m0) {
    __shared__ __align__(16) unsigned short As[128 * 64];
    __shared__ __align__(16) unsigned short Bs[128 * 64];
    const int nbm = gridDim.x / nbn;
    const int stripe = nbm >> 3;                 // bm rows per XCD
    const int xcd = blockIdx.x & 7;
    const int loc = blockIdx.x >> 3;
    const int bm = xcd * stripe + (loc % stripe);
    const int bn = loc / stripe;
    const int tid = threadIdx.x;
    const int wave = tid >> 6;
    const int lane = tid & 63;
    const int wm = (wave >> 1) << 6;             // wave row offset
    const int wn = (wave & 1) << 6;              // wave col offset
    // staging: inst i covers phys rows i*32 + wave*8 + (lane>>3), phys group
    // lane&7; the element fetched is logical group (lane&7)^(lane>>3) (r&7 ==
    // lane>>3 since i*32, wave*8 are multiples of 8).
    const int srow = (wave << 3) + (lane >> 3);          // + i*32
    const int scol = (((lane & 7) ^ (lane >> 3)) << 3);  // logical col (elems)
    const unsigned short* Ab = A + (long)(bm * 128) * lda;
    const unsigned short* Bb = Bt + (long)(bn * 128) * Kd;

    f32x4_t acc[4][4];
    #pragma unroll
    for (int i = 0; i < 4; ++i)
        #pragma unroll
        for (int j = 0; j < 4; ++j)
            acc[i][j] = (f32x4_t){0.f, 0.f, 0.f, 0.f};

    const int fr = lane & 15;            // fragment row (m for A, n for B)
    const int quad = lane >> 4;          // k-quad

    for (int k0 = 0; k0 < Kd; k0 += 64) {
        #pragma unroll
        for (int i = 0; i < 4; ++i) {
            load_lds16(Ab + (long)(srow + i * 32) * lda + k0 + scol,
                       As + ((i * 32 + (wave << 3)) << 6));
            load_lds16(Bb + (long)(srow + i * 32) * Kd + k0 + scol,
                       Bs + ((i * 32 + (wave << 3)) << 6));
        }
        __syncthreads();   // drains vmcnt -> staging complete
        #pragma unroll
        for (int h = 0; h < 2; ++h) {
            bf16x8_t af[4], bfr[4];
            #pragma unroll
            for (int i = 0; i < 4; ++i) {
                const int row = wm + (i << 4) + fr;
                const int pg = (quad + (h << 2)) ^ (fr & 7);   // row&7 == fr&7
                af[i] = *(const bf16x8_t*)&As[(row << 6) + (pg << 3)];
            }
            #pragma unroll
            for (int j = 0; j < 4; ++j) {
                const int row = wn + (j << 4) + fr;
                const int pg = (quad + (h << 2)) ^ (fr & 7);
                bfr[j] = *(const bf16x8_t*)&Bs[(row << 6) + (pg << 3)];
            }
            #pragma unroll
            for (int i = 0; i < 4; ++i)
                #pragma unroll
                for (int j = 0; j < 4; ++j)
                    acc[i][j] = __builtin_amdgcn_mfma_f32_16x16x32_bf16(
                        af[i], bfr[j], acc[i][j], 0, 0, 0);
        }
        __syncthreads();   // all waves done reading before next staging
    }

    // epilogue — C/D layout: col = lane&15, row = (lane>>4)*4 + reg
    const int gcol0 = bn * 128 + wn;
    const int grow0 = bm * 128 + wm;
    #pragma unroll
    for (int j = 0; j < 4; ++j) {
        const int n = gcol0 + (j << 4) + (lane & 15);
        const float bv = bias[n];
        #pragma unroll
        for (int i = 0; i < 4; ++i) {
            #pragma unroll
            for (int r = 0; r < 4; ++r) {
                const int m = grow0 + (i << 4) + ((lane >> 4) << 2) + r;
                float v = acc[i][j][r] + bv;
                if (ACT == 1) v = fmaxf(v, 0.f);
                if (ACT == 2) v = 1.f / (1.f + __expf(-v));
                if (WMODE == 0) {
                    C0u[(long)m * ldc + n] = f2bf(v);
                } else if (WMODE == 1) {
                    const int gm = m0 + m;
                    C1f[((long)(gm >> 6) * 512 + n) * 64 + (gm & 63)] = v;
                    if (n < 256) C0u[(long)m * 256 + n] = f2bf(v);
                } else {
                    const int gm = m0 + m;
                    const int b = gm >> 6, g6 = gm & 63;
                    const int gh = g6 >> 3, gw = g6 & 7;
                    const int c = n >> 8, kh = (n >> 4) & 15, kw = n & 15;
                    const long o = (long)(b * 3 + c) * 16384
                                 + ((gh << 4) + kh) * 128 + (gw << 4) + kw;
                    C0f[o] = v;
                }
            }
        }
    }
}

// ---------- launch ----------
extern "C" void kernel_launch(void* const* d_in, const int* in_sizes, int n_in,
                              void* d_out, int out_size, void* d_ws, size_t ws_size,
                              hipStream_t stream) {
    const float* x      = (const float*)d_in[0];
    const float* w_enc1 = (const float*)d_in[1];
    const float* b_enc1 = (const float*)d_in[2];
    const float* w_enc2 = (const float*)d_in[3];
    const float* b_enc2 = (const float*)d_in[4];
    const float* w_dec1 = (const float*)d_in[5];
    const float* b_dec1 = (const float*)d_in[6];
    const float* w_dec2 = (const float*)d_in[7];
    const float* b_dec2 = (const float*)d_in[8];
    float* outf = (float*)d_out;                      // f32 output
    unsigned short* patches = (unsigned short*)d_out; // patches bf16 in out0 u16 view
    float* out_ml = outf + (long)MM * PP;             // f32 [12.58M, 20.97M)

    // Scratch: prefer d_ws (single 16384-row chunk, 84.9 MB); else fall back
    // to x's dead buffer with two 8192-row chunks in REVERSE order (round-9
    // proven: GEMM4's f32 writes never land on patches a later chunk needs).
    const size_t WT_ELEMS = 2048 * 768 + 512 * 2048 + 2048 * 256 + 768 * 2048;
    unsigned short* sb;
    long Mc;
    if (ws_size >= (WT_ELEMS + (size_t)MM * (LL + HID)) * 2) {
        sb = (unsigned short*)d_ws;  Mc = MM;         // 16384 rows, 1 chunk
    } else {
        sb = (unsigned short*)d_in[0]; Mc = 8192;     // x-buffer, 2 chunks
    }
    unsigned short* wT1 = sb;                         // 2048*768
    unsigned short* wT2 = wT1 + 2048 * 768;           // 512*2048
    unsigned short* wT3 = wT2 + 512 * 2048;           // 2048*256
    unsigned short* wT4 = wT3 + 2048 * 256;           // 768*2048
    unsigned short* mu  = wT4 + 768 * 2048;           // Mc*256
    unsigned short* he  = mu + Mc * LL;               // Mc*2048 (hd aliases he)

    patchify<<<6144, 256, 0, stream>>>(x, patches);

    transpose_k<<<(768 / 32) * (2048 / 32), 256, 0, stream>>>(w_enc1, wT1, 768, 2048);
    transpose_k<<<(2048 / 32) * (512 / 32), 256, 0, stream>>>(w_enc2, wT2, 2048, 512);
    transpose_k<<<(256 / 32) * (2048 / 32), 256, 0, stream>>>(w_dec1, wT3, 256, 2048);
    transpose_k<<<(2048 / 32) * (768 / 32), 256, 0, stream>>>(w_dec2, wT4, 2048, 768);

    const int nbm = (int)(Mc / 128);   // 128 or 64, divisible by 8
    for (long m0 = MM - Mc; m0 >= 0; m0 -= Mc) {
        // he = relu(patches[m0:] @ w_enc1 + b_enc1)      Mc x 2048, K=768
        gemm_bt<1, 0><<<nbm * (HID / 128), 256, 0, stream>>>(
            patches + m0 * PP, PP, wT1, b_enc1,
            he, nullptr, nullptr, HID, PP, HID / 128, 0);
        // ml = he @ w_enc2 + b_enc2 -> out1 f32 (transposed) + compact bf16 mu
        gemm_bt<0, 1><<<nbm * (512 / 128), 256, 0, stream>>>(
            he, HID, wT2, b_enc2,
            mu, nullptr, out_ml, 0, HID, 512 / 128, (int)m0);
        // hd = relu(mu @ w_dec1 + b_dec1)                Mc x 2048, K=256
        gemm_bt<1, 0><<<nbm * (HID / 128), 256, 0, stream>>>(
            mu, LL, wT3, b_dec1,
            he, nullptr, nullptr, HID, LL, HID / 128, 0);
        // recon rows m0.. = sigmoid(hd @ w_dec2 + b_dec2) -> f32 scatter out0
        gemm_bt<2, 2><<<nbm * (PP / 128), 256, 0, stream>>>(
            he, HID, wT4, b_dec2,
            nullptr, outf, nullptr, 0, HID, PP / 128, (int)m0);
    }
}